// Round 8
// baseline (74.619 us; speedup 1.0000x reference)
//
#include <hip/hip_runtime.h>
#include <math.h>

// Problem constants (reference: pos [64,1024,3] fp32, rad=0.15)
#define TN     64
#define NP     1024
#define RADIUS 0.15f
#define MIN_D  (2.0f * RADIUS)
#define R2     (MIN_D * MIN_D)

#define SPLIT  16                  // blocks per timestep -> 1024 blocks = 4/CU, one round
#define GI     16                  // i-rows register-tiled per j sweep
#define NGRP   (NP / GI)           // 64 groups per timestep
#define GPB    (NGRP / SPLIT)      // 4 groups per block
#define BLOCK  256
#define NBLK   (TN * SPLIT)        // 1024 blocks

#define FLAG_MAGIC 0x5EED5EEDu     // != 0xAAAAAAAA poison, != 0 fresh-alloc

// Single fused dispatch: each block publishes {cnt, loss, flag} to ws with
// agent-scope release; block 0 spin-acquires all 1024 flags, sums, writes out.
// Deadlock-free: only block 0 ever waits; all other blocks run to completion
// regardless of scheduling (they free their slots). Replay-safe: ws re-poisoned
// per launch, and even a stale flag would expose identical (deterministic) data.
__launch_bounds__(BLOCK, 4)   // 128 VGPR budget; i-tile stays resident
__global__ void fused_kernel(const float* __restrict__ pos,
                             unsigned int* __restrict__ ws,
                             float* __restrict__ out) {
    // interleaved x,y,z: float4 staging, stride-3 j-reads = 2 lanes/bank (free)
    __shared__ float sh[NP * 3];
    const int bid   = blockIdx.x;
    const int t     = bid / SPLIT;
    const int split = bid % SPLIT;
    const int tid   = threadIdx.x;

    const float4* p4  = (const float4*)(pos + (size_t)t * NP * 3);
    float4*       sh4 = (float4*)sh;
    #pragma unroll
    for (int i = 0; i < (NP * 3 / 4) / BLOCK; ++i)     // 3 iters
        sh4[tid + i * BLOCK] = p4[tid + i * BLOCK];
    __syncthreads();

    unsigned int cnt = 0;
    float loss = 0.0f;

    #pragma unroll
    for (int m = 0; m < GPB; ++m) {
        // snake: per-block total tail length constant -> perfect load balance
        const int g = (m & 1) ? (m * SPLIT + (SPLIT - 1 - split))
                              : (m * SPLIT + split);
        const int b = g * GI;

        float xi[GI], yi[GI], zi[GI];
        #pragma unroll
        for (int k = 0; k < GI; ++k) {
            xi[k] = sh[3 * (b + k) + 0];
            yi[k] = sh[3 * (b + k) + 1];
            zi[k] = sh[3 * (b + k) + 2];
        }
        // Opaque barrier: pins the 48-value i-tile in VGPRs (prevents LDS remat,
        // which cost ~56 lane-ops/pair in R2: VGPR_Count=32 evidence).
        #pragma unroll
        for (int k = 0; k < GI; ++k)
            asm volatile("" : "+v"(xi[k]), "+v"(yi[k]), "+v"(zi[k]));

        // head: in-group pairs, j in (b, b+GI), one lane per j (tiny, once/group)
        if (tid < GI - 1) {
            const int j = b + 1 + tid;
            const float xj = sh[3 * j], yj = sh[3 * j + 1], zj = sh[3 * j + 2];
            #pragma unroll
            for (int k = 0; k < GI; ++k) {
                if (k <= tid) {                        // i = b+k < j
                    const float dx = xi[k] - xj;
                    const float dy = yi[k] - yj;
                    const float dz = zi[k] - zj;
                    const float d2 = dx * dx + dy * dy + dz * dz;
                    cnt += (d2 < R2) ? 1u : 0u;
                    const float pen = fmaxf(MIN_D - __builtin_amdgcn_sqrtf(d2), 0.0f);
                    loss += pen * pen;
                }
            }
        }

        // tail: branchless (hits aren't rare at wave granularity), one sqrt/pair;
        // non-hit contributes pen = max(MIN_D - sqrt(d2), 0) = 0 exactly.
        #pragma unroll 2
        for (int j = b + GI + tid; j < NP; j += BLOCK) {
            const float xj = sh[3 * j], yj = sh[3 * j + 1], zj = sh[3 * j + 2];
            #pragma unroll
            for (int k = 0; k < GI; ++k) {
                const float dx = xi[k] - xj;
                const float dy = yi[k] - yj;
                const float dz = zi[k] - zj;
                const float d2 = dx * dx + dy * dy + dz * dz;
                cnt += (d2 < R2) ? 1u : 0u;            // v_cmp + v_addc (vcc only)
                const float pen = fmaxf(MIN_D - __builtin_amdgcn_sqrtf(d2), 0.0f);
                loss += pen * pen;
            }
        }
    }

    // block reduction #1: wave shuffle then cross-wave LDS
    float fcnt = (float)cnt;
    #pragma unroll
    for (int off = 32; off > 0; off >>= 1) {
        fcnt += __shfl_down(fcnt, off);
        loss += __shfl_down(loss, off);
    }
    __shared__ float cs[BLOCK / 64], ls[BLOCK / 64];
    const int wave = tid >> 6;
    if ((tid & 63) == 0) { cs[wave] = fcnt; ls[wave] = loss; }
    __syncthreads();

    // publish this block's partial with agent-scope release (cross-XCD visible)
    if (tid == 0) {
        float c = 0.0f, l = 0.0f;
        #pragma unroll
        for (int w = 0; w < BLOCK / 64; ++w) { c += cs[w]; l += ls[w]; }
        __hip_atomic_store(&ws[3 * bid + 0], __float_as_uint(c),
                           __ATOMIC_RELAXED, __HIP_MEMORY_SCOPE_AGENT);
        __hip_atomic_store(&ws[3 * bid + 1], __float_as_uint(l),
                           __ATOMIC_RELAXED, __HIP_MEMORY_SCOPE_AGENT);
        __hip_atomic_store(&ws[3 * bid + 2], FLAG_MAGIC,
                           __ATOMIC_RELEASE, __HIP_MEMORY_SCOPE_AGENT);
    }

    if (bid != 0) return;

    // block 0: consume all 1024 partials (4 slots/thread), then reduce + store.
    __syncthreads();   // tid0 done reading cs/ls above -> safe to reuse them below
    float sc = 0.0f, sl = 0.0f;
    #pragma unroll
    for (int i = 0; i < NBLK / BLOCK; ++i) {
        const int s = tid + i * BLOCK;
        while (__hip_atomic_load(&ws[3 * s + 2], __ATOMIC_ACQUIRE,
                                 __HIP_MEMORY_SCOPE_AGENT) != FLAG_MAGIC) { }
        sc += __uint_as_float(__hip_atomic_load(&ws[3 * s + 0], __ATOMIC_RELAXED,
                                                __HIP_MEMORY_SCOPE_AGENT));
        sl += __uint_as_float(__hip_atomic_load(&ws[3 * s + 1], __ATOMIC_RELAXED,
                                                __HIP_MEMORY_SCOPE_AGENT));
    }
    #pragma unroll
    for (int off = 32; off > 0; off >>= 1) {
        sc += __shfl_down(sc, off);
        sl += __shfl_down(sl, off);
    }
    if ((tid & 63) == 0) { cs[wave] = sc; ls[wave] = sl; }
    __syncthreads();
    if (tid == 0) {
        float ct = 0.0f, lt = 0.0f;
        #pragma unroll
        for (int w = 0; w < BLOCK / 64; ++w) { ct += cs[w]; lt += ls[w]; }
        out[0] = ct;   // harness reads d_out as float32; count exact (< 2^24)
        out[1] = lt;
    }
}

extern "C" void kernel_launch(void* const* d_in, const int* in_sizes, int n_in,
                              void* d_out, int out_size, void* d_ws, size_t ws_size,
                              hipStream_t stream) {
    const float*  pos = (const float*)d_in[0];
    unsigned int* ws  = (unsigned int*)d_ws;
    float*        out = (float*)d_out;

    fused_kernel<<<NBLK, BLOCK, 0, stream>>>(pos, ws, out);
}

// Round 9
// 74.390 us; speedup vs baseline: 1.0031x; 1.0031x over previous
//
#include <hip/hip_runtime.h>
#include <math.h>

// Problem constants (reference: pos [64,1024,3] fp32, rad=0.15)
#define TN     64
#define NP     1024
#define RADIUS 0.15f
#define MIN_D  (2.0f * RADIUS)
#define R2     (MIN_D * MIN_D)

#define SPLIT  16                  // blocks per timestep -> 1024 blocks = 4/CU, one round
#define GI     16                  // i-rows per group (tile lives in SGPRs)
#define NGRP   (NP / GI)           // 64 groups per timestep
#define GPB    (NGRP / SPLIT)      // 4 groups per block
#define BLOCK  256
#define NBLK   (TN * SPLIT)        // 1024 blocks

#define FLAG_MAGIC 0x5EED5EEDu     // != 0xAAAAAAAA poison, != 0 fresh-alloc

// Single fused dispatch; block 0 consumes all partials (agent-scope acq/rel).
// Key change vs R8: i-tile is loaded from GLOBAL with block-uniform addresses
// -> s_load into SGPRs (SMEM path; zero LDS, zero VALU), pinned with "+s".
// j-points sit in LDS as padded float4 -> one ds_read_b128 per j instead of
// 3 ds_read_b32. Removes ~1150 of ~1290 LDS cycles/wave (the real R4-R8 cost).
__launch_bounds__(BLOCK, 4)
__global__ void fused_kernel(const float* __restrict__ pos,
                             unsigned int* __restrict__ ws,
                             float* __restrict__ out) {
    __shared__ float4 shp[NP];     // x,y,z,pad per point: b128-friendly, conflict-free
    const int bid   = blockIdx.x;
    const int t     = bid / SPLIT;
    const int split = bid % SPLIT;
    const int tid   = threadIdx.x;

    // stage + repack: thread u reads 3 float4 (12 floats = points 4u..4u+3),
    // writes 4 padded float4. 786 KB input is L2-resident after first touch.
    {
        const float4* p4 = (const float4*)(pos + (size_t)t * NP * 3);
        const float4 a = p4[3 * tid + 0];
        const float4 b = p4[3 * tid + 1];
        const float4 c = p4[3 * tid + 2];
        shp[4 * tid + 0] = make_float4(a.x, a.y, a.z, 0.0f);
        shp[4 * tid + 1] = make_float4(a.w, b.x, b.y, 0.0f);
        shp[4 * tid + 2] = make_float4(b.z, b.w, c.x, 0.0f);
        shp[4 * tid + 3] = make_float4(c.y, c.z, c.w, 0.0f);
    }
    __syncthreads();

    unsigned int cnt = 0;
    float loss = 0.0f;

    #pragma unroll 1               // keep one group's 48 SGPRs live at a time
    for (int m = 0; m < GPB; ++m) {
        // snake: per-block total tail length constant -> perfect load balance
        const int g = (m & 1) ? (m * SPLIT + (SPLIT - 1 - split))
                              : (m * SPLIT + split);
        const int b = g * GI;

        // i-tile from global with UNIFORM addresses -> s_load -> SGPRs
        const float* tp = pos + (size_t)t * NP * 3 + 3 * b;
        float xi[GI], yi[GI], zi[GI];
        #pragma unroll
        for (int k = 0; k < GI; ++k) {
            xi[k] = tp[3 * k + 0];
            yi[k] = tp[3 * k + 1];
            zi[k] = tp[3 * k + 2];
        }
        // Pin to SGPRs + block rematerialization (R2 evidence: without a pin the
        // allocator re-reads operands per j-iteration).
        #pragma unroll
        for (int k = 0; k < GI; ++k)
            asm volatile("" : "+s"(xi[k]), "+s"(yi[k]), "+s"(zi[k]));

        // head: in-group pairs, j in (b, b+GI), one lane per j (tiny, once/group)
        if (tid < GI - 1) {
            const int j = b + 1 + tid;
            const float4 pj = shp[j];
            #pragma unroll
            for (int k = 0; k < GI; ++k) {
                if (k <= tid) {                        // i = b+k < j
                    const float dx = xi[k] - pj.x;
                    const float dy = yi[k] - pj.y;
                    const float dz = zi[k] - pj.z;
                    const float d2 = dx * dx + dy * dy + dz * dz;
                    cnt += (d2 < R2) ? 1u : 0u;
                    const float pen = fmaxf(MIN_D - __builtin_amdgcn_sqrtf(d2), 0.0f);
                    loss += pen * pen;
                }
            }
        }

        // tail: branchless, one ds_read_b128 per j, 12 VALU per pair
        // (non-hit: pen = max(MIN_D - sqrt(d2), 0) = 0 exactly)
        #pragma unroll 2
        for (int j = b + GI + tid; j < NP; j += BLOCK) {
            const float4 pj = shp[j];
            #pragma unroll
            for (int k = 0; k < GI; ++k) {
                const float dx = xi[k] - pj.x;         // v_sub_f32 (sgpr, vgpr)
                const float dy = yi[k] - pj.y;
                const float dz = zi[k] - pj.z;
                const float d2 = dx * dx + dy * dy + dz * dz;
                cnt += (d2 < R2) ? 1u : 0u;            // v_cmp + v_addc (vcc only)
                const float pen = fmaxf(MIN_D - __builtin_amdgcn_sqrtf(d2), 0.0f);
                loss += pen * pen;
            }
        }
    }

    // block reduction: wave shuffle then cross-wave LDS
    float fcnt = (float)cnt;
    #pragma unroll
    for (int off = 32; off > 0; off >>= 1) {
        fcnt += __shfl_down(fcnt, off);
        loss += __shfl_down(loss, off);
    }
    __shared__ float cs[BLOCK / 64], ls[BLOCK / 64];
    const int wave = tid >> 6;
    if ((tid & 63) == 0) { cs[wave] = fcnt; ls[wave] = loss; }
    __syncthreads();

    // publish this block's partial with agent-scope release (cross-XCD visible)
    if (tid == 0) {
        float c = 0.0f, l = 0.0f;
        #pragma unroll
        for (int w = 0; w < BLOCK / 64; ++w) { c += cs[w]; l += ls[w]; }
        __hip_atomic_store(&ws[3 * bid + 0], __float_as_uint(c),
                           __ATOMIC_RELAXED, __HIP_MEMORY_SCOPE_AGENT);
        __hip_atomic_store(&ws[3 * bid + 1], __float_as_uint(l),
                           __ATOMIC_RELAXED, __HIP_MEMORY_SCOPE_AGENT);
        __hip_atomic_store(&ws[3 * bid + 2], FLAG_MAGIC,
                           __ATOMIC_RELEASE, __HIP_MEMORY_SCOPE_AGENT);
    }

    if (bid != 0) return;

    // block 0: consume all 1024 partials (4 slots/thread), reduce, store out.
    __syncthreads();   // tid0 finished reading cs/ls -> safe to reuse
    float sc = 0.0f, sl = 0.0f;
    #pragma unroll
    for (int i = 0; i < NBLK / BLOCK; ++i) {
        const int s = tid + i * BLOCK;
        while (__hip_atomic_load(&ws[3 * s + 2], __ATOMIC_ACQUIRE,
                                 __HIP_MEMORY_SCOPE_AGENT) != FLAG_MAGIC) { }
        sc += __uint_as_float(__hip_atomic_load(&ws[3 * s + 0], __ATOMIC_RELAXED,
                                                __HIP_MEMORY_SCOPE_AGENT));
        sl += __uint_as_float(__hip_atomic_load(&ws[3 * s + 1], __ATOMIC_RELAXED,
                                                __HIP_MEMORY_SCOPE_AGENT));
    }
    #pragma unroll
    for (int off = 32; off > 0; off >>= 1) {
        sc += __shfl_down(sc, off);
        sl += __shfl_down(sl, off);
    }
    if ((tid & 63) == 0) { cs[wave] = sc; ls[wave] = sl; }
    __syncthreads();
    if (tid == 0) {
        float ct = 0.0f, lt = 0.0f;
        #pragma unroll
        for (int w = 0; w < BLOCK / 64; ++w) { ct += cs[w]; lt += ls[w]; }
        out[0] = ct;   // harness reads d_out as float32; count exact (< 2^24)
        out[1] = lt;
    }
}

extern "C" void kernel_launch(void* const* d_in, const int* in_sizes, int n_in,
                              void* d_out, int out_size, void* d_ws, size_t ws_size,
                              hipStream_t stream) {
    const float*  pos = (const float*)d_in[0];
    unsigned int* ws  = (unsigned int*)d_ws;
    float*        out = (float*)d_out;

    fused_kernel<<<NBLK, BLOCK, 0, stream>>>(pos, ws, out);
}